// Round 1
// baseline (239.395 us; speedup 1.0000x reference)
//
#include <hip/hip_runtime.h>
#include <hip/hip_fp16.h>

#define NTOK 392
#define NC 128
#define STRIPS 25
#define PI_F 3.14159265358979323846f

typedef __bf16 bf16_t;
typedef bf16_t bf16x8 __attribute__((ext_vector_type(8)));
typedef unsigned short u16;
typedef u16 u16x8 __attribute__((ext_vector_type(8)));
typedef float f32x4 __attribute__((ext_vector_type(4)));

union Frag { u16x8 u; bf16x8 b; };

__device__ __forceinline__ u16 f2bf(float f) {
    unsigned u = __float_as_uint(f);
    unsigned r = (u + 0x7FFFu + ((u >> 16) & 1u)) >> 16;
    return (u16)r;
}
__device__ __forceinline__ float bf2f(u16 u) {
    return __uint_as_float(((unsigned)u) << 16);
}

// ---------------------------------------------------------------------------
// prep kernel: weights -> bf16 MFMA-B-fragment-linear layout + colsums
// wfrag[set][nt][ks][lane][8] : element i = W_set[k = ks*32+(lane>>4)*8+i][col = nt*16+(lane&15)]
// ---------------------------------------------------------------------------
__global__ void prep_kernel(const float* __restrict__ w_value,
                            const float* __restrict__ w_off,
                            const float* __restrict__ w_attn,
                            const float* __restrict__ w_out,
                            const float* __restrict__ w_proj,
                            u16* __restrict__ wfrag,
                            float* __restrict__ colsum) {
    int g = blockIdx.x * 256 + threadIdx.x;
    if (g < 8192) {
        int lane = g & 63;
        int ks = (g >> 6) & 3;
        int nt = (g >> 8) & 7;
        int set = g >> 11;
        int col = nt * 16 + (lane & 15);
        int k0 = ks * 32 + ((lane >> 4) << 3);
#pragma unroll
        for (int i = 0; i < 8; i++) {
            int k = k0 + i;
            float v;
            if (set == 0)      v = w_value[k * 128 + col];
            else if (set == 1) v = (col < 96) ? w_off[k * 96 + col] : w_attn[k * 32 + col - 96];
            else if (set == 2) v = w_out[k * 128 + col];
            else               v = w_proj[k * 128 + col];
            wfrag[(size_t)g * 8 + i] = f2bf(v);
        }
    } else if (g < 8192 + 128) {
        int o = g - 8192;
        float s = 0.f;
        for (int c2 = 0; c2 < 128; c2++)
            s += (o < 96) ? w_off[c2 * 96 + o] : w_attn[c2 * 32 + o - 96];
        colsum[o] = s;
    }
}

// A-frags in regs, B-frags streamed from global fraglinear table (L2-hot).
__device__ __forceinline__ void gemm8(const Frag* A, const u16* __restrict__ wf,
                                      int set, int lane, f32x4* C) {
#pragma unroll
    for (int nt = 0; nt < 8; nt++) {
        f32x4 acc = {0.f, 0.f, 0.f, 0.f};
#pragma unroll
        for (int ks = 0; ks < 4; ks++) {
            Frag B;
            B.u = *(const u16x8*)(wf + ((size_t)(((set * 8 + nt) * 4 + ks) * 64 + lane)) * 8);
            acc = __builtin_amdgcn_mfma_f32_16x16x32_bf16(A[ks].b, B.b, acc, 0, 0, 0);
        }
        C[nt] = acc;
    }
}

__device__ __forceinline__ u16x8 pack8(float4 a, float4 b) {
    u16x8 r;
    r[0] = f2bf(a.x); r[1] = f2bf(a.y); r[2] = f2bf(a.z); r[3] = f2bf(a.w);
    r[4] = f2bf(b.x); r[5] = f2bf(b.y); r[6] = f2bf(b.z); r[7] = f2bf(b.w);
    return r;
}

// ---------------------------------------------------------------------------
// fused kernel: one block per window b (512 threads = 8 waves)
// ---------------------------------------------------------------------------
__global__ __launch_bounds__(512, 2) void fused_kernel(
    const float* __restrict__ x, const float* __restrict__ mask,
    const u16* __restrict__ wfrag, const float* __restrict__ colsum_ws,
    const float* __restrict__ b_value, const float* __restrict__ b_off,
    const float* __restrict__ b_attn, const float* __restrict__ b_out,
    const float* __restrict__ b_proj, const float* __restrict__ ln_g,
    const float* __restrict__ ln_b, float* __restrict__ out) {
    __shared__ u16 value_lds[NTOK * NC];        // bf16 grid (d,h,w) x (head*16+hd)
    __shared__ u16 scr[8][2048];                // per-wave scratch (off/aw fp16, then attnout/LN bf16)
    __shared__ float diag_lds[NTOK];
    __shared__ float colsum_lds[128], bias2_lds[128], bval_lds[128];
    __shared__ float bout_lds[128], lng_lds[128], lnb_lds[128], bproj_lds[128];

    const int b = blockIdx.x;
    const int tid = threadIdx.x;
    const int lane = tid & 63;
    const int wv = tid >> 6;
    const float* xb = x + (size_t)b * NTOK * NC;
    float* outb = out + (size_t)b * NTOK * NC;

    // ---- phase 0: diag from mask + misc loads ----
    if (tid < NTOK) {
        int n = tid;
        int d = n / 49; int rr = n - d * 49; int h = rr / 7; int w = rr - h * 7;
        const float* mb = mask + ((size_t)b * NTOK + n) * NTOK;
        float sz = 0.f, sy = 0.f, sx = 0.f;
        for (int k = 0; k <= d; k++) sz += mb[k * 49 + h * 7 + w];
        for (int k = 0; k <= h; k++) sy += mb[d * 49 + k * 7 + w];
        for (int k = 0; k <= w; k++) sx += mb[d * 49 + h * 7 + k];
        float m = mb[d * 49 + h * 7 + w];
        float xe = sx * m / PI_F, ye = sy * m / PI_F, ze = sz * m / PI_F;
        diag_lds[n] = m * (sinf(xe) + sinf(PI_F * ye) + ze);
    }
    if (tid < 128) {
        colsum_lds[tid] = colsum_ws[tid];
        bias2_lds[tid] = (tid < 96) ? b_off[tid] : b_attn[tid - 96];
        bval_lds[tid] = b_value[tid];
        bout_lds[tid] = b_out[tid];
        lng_lds[tid] = ln_g[tid];
        lnb_lds[tid] = ln_b[tid];
        bproj_lds[tid] = b_proj[tid];
    }
    __syncthreads();

    // ---- phase V: value = x @ w_value + b_value -> value_lds (bf16) ----
    for (int s = wv; s < STRIPS; s += 8) {
        int t0 = s * 16;
        int arow = t0 + (lane & 15); if (arow > NTOK - 1) arow = NTOK - 1;
        Frag A[4];
#pragma unroll
        for (int ks = 0; ks < 4; ks++) {
            const float4* p = (const float4*)(xb + (size_t)arow * NC + ks * 32 + ((lane >> 4) << 3));
            A[ks].u = pack8(p[0], p[1]);
        }
        f32x4 C[8];
        gemm8(A, wfrag, 0, lane, C);
#pragma unroll
        for (int nt = 0; nt < 8; nt++) {
            int col = nt * 16 + (lane & 15);
            float bv = bval_lds[col];
#pragma unroll
            for (int reg = 0; reg < 4; reg++) {
                int r = t0 + ((lane >> 4) << 2) + reg;
                if (r < NTOK) value_lds[r * NC + col] = f2bf(C[nt][reg] + bv);
            }
        }
    }
    __syncthreads();

    // ---- phase O: per strip, fully fused off/attn -> sample -> out -> LN -> proj ----
    for (int s = wv; s < STRIPS; s += 8) {
        int t0 = s * 16;
        int arow = t0 + (lane & 15); if (arow > NTOK - 1) arow = NTOK - 1;
        Frag A1[4];
#pragma unroll
        for (int ks = 0; ks < 4; ks++) {
            const float4* p = (const float4*)(xb + (size_t)arow * NC + ks * 32 + ((lane >> 4) << 3));
            A1[ks].u = pack8(p[0], p[1]);
        }
        f32x4 C1[8];
        gemm8(A1, wfrag, 1, lane, C1);

        // diag*colsum + bias; softmax over the 4 attn logits (4 adjacent lanes)
#pragma unroll
        for (int nt = 0; nt < 8; nt++) {
            int col = nt * 16 + (lane & 15);
            float cs = colsum_lds[col];
            float b2 = bias2_lds[col];
#pragma unroll
            for (int reg = 0; reg < 4; reg++) {
                int r = ((lane >> 4) << 2) + reg;
                int gt = t0 + r;
                float dg = diag_lds[gt < NTOK ? gt : NTOK - 1];
                float v = C1[nt][reg] + dg * cs + b2;
                if (nt < 6) {
                    scr[wv][r * 96 + col] = __half_as_ushort(__float2half(v));
                } else {
                    float m = fmaxf(v, __shfl_xor(v, 1));
                    m = fmaxf(m, __shfl_xor(m, 2));
                    float e = expf(v - m);
                    float s2 = e + __shfl_xor(e, 1);
                    s2 += __shfl_xor(s2, 2);
                    scr[wv][1536 + r * 32 + (col - 96)] =
                        __half_as_ushort(__float2half(e / s2));
                }
            }
        }

        // trilinear sampling: lane -> (token row = lane>>3, head = lane&7), 2 passes
        float acc[2][16];
#pragma unroll
        for (int j = 0; j < 2; j++)
#pragma unroll
            for (int e = 0; e < 16; e++) acc[j][e] = 0.f;

#pragma unroll
        for (int j = 0; j < 2; j++) {
            int t = j * 8 + (lane >> 3);
            int hh = lane & 7;
            int gt = t0 + t;
            int gtc = gt < NTOK ? gt : NTOK - 1;
            int dd = gtc / 49; int rr = gtc - dd * 49;
            int hy = rr / 7;   int wq = rr - hy * 7;
#pragma unroll
            for (int p = 0; p < 4; p++) {
                int ob = t * 96 + (hh * 4 + p) * 3;
                float ox = __half2float(__ushort_as_half(scr[wv][ob + 0]));
                float oy = __half2float(__ushort_as_half(scr[wv][ob + 1]));
                float oz = __half2float(__ushort_as_half(scr[wv][ob + 2]));
                float aw = __half2float(__ushort_as_half(scr[wv][1536 + t * 32 + hh * 4 + p]));
                float px = (float)wq + ox;
                float py = (float)hy + oy;
                float pz = (float)dd + oz;
                float fx = floorf(px), fy = floorf(py), fz = floorf(pz);
                float wxf = px - fx, wyf = py - fy, wzf = pz - fz;
                int ix = (int)fx, iy = (int)fy, iz = (int)fz;
#pragma unroll
                for (int c = 0; c < 8; c++) {
                    int dx = c & 1, dy = (c >> 1) & 1, dz = c >> 2;
                    int xi = ix + dx, yi = iy + dy, zi = iz + dz;
                    if (xi < 0 || xi >= 7 || yi < 0 || yi >= 7 || zi < 0 || zi >= 8) continue;
                    float wgt = (dx ? wxf : 1.f - wxf) * (dy ? wyf : 1.f - wyf)
                              * (dz ? wzf : 1.f - wzf) * aw;
                    const u16x8* vp =
                        (const u16x8*)&value_lds[(zi * 49 + yi * 7 + xi) * NC + hh * 16];
                    u16x8 v0 = vp[0], v1 = vp[1];
#pragma unroll
                    for (int e = 0; e < 8; e++) {
                        acc[j][e]     += wgt * bf2f(v0[e]);
                        acc[j][8 + e] += wgt * bf2f(v1[e]);
                    }
                }
            }
        }

        // attnout strip -> scratch (bf16, XOR-swizzled for conflict-free A-frag reads)
#pragma unroll
        for (int j = 0; j < 2; j++) {
            int t = j * 8 + (lane >> 3);
            int hh = lane & 7;
            int sw = (t & 7) << 3;
            u16x8 o0, o1;
#pragma unroll
            for (int e = 0; e < 8; e++) { o0[e] = f2bf(acc[j][e]); o1[e] = f2bf(acc[j][8 + e]); }
            *(u16x8*)&scr[wv][t * NC + ((hh * 16) ^ sw)] = o0;
            *(u16x8*)&scr[wv][t * NC + ((hh * 16 + 8) ^ sw)] = o1;
        }

        // w_out GEMM
        Frag A2[4];
#pragma unroll
        for (int ks = 0; ks < 4; ks++) {
            int rowt = lane & 15;
            int c0 = ks * 32 + ((lane >> 4) << 3);
            A2[ks].u = *(const u16x8*)&scr[wv][rowt * NC + (c0 ^ ((rowt & 7) << 3))];
        }
        f32x4 C2[8];
        gemm8(A2, wfrag, 2, lane, C2);

        // residual + LayerNorm (fp32), staged bf16 back to scratch
#pragma unroll
        for (int reg = 0; reg < 4; reg++) {
            int r = ((lane >> 4) << 2) + reg;
            int gt = t0 + r;
            int gtc = gt < NTOK ? gt : NTOK - 1;
            float vrow[8];
            float sm = 0.f, sq = 0.f;
#pragma unroll
            for (int nt = 0; nt < 8; nt++) {
                int col = nt * 16 + (lane & 15);
                float v = C2[nt][reg] + bout_lds[col] + xb[(size_t)gtc * NC + col];
                vrow[nt] = v; sm += v; sq += v * v;
            }
            sm += __shfl_xor(sm, 1); sm += __shfl_xor(sm, 2);
            sm += __shfl_xor(sm, 4); sm += __shfl_xor(sm, 8);
            sq += __shfl_xor(sq, 1); sq += __shfl_xor(sq, 2);
            sq += __shfl_xor(sq, 4); sq += __shfl_xor(sq, 8);
            float mu = sm * (1.f / 128.f);
            float var = sq * (1.f / 128.f) - mu * mu;
            float rs = rsqrtf(var + 1e-5f);
#pragma unroll
            for (int nt = 0; nt < 8; nt++) {
                int col = nt * 16 + (lane & 15);
                float xn = (vrow[nt] - mu) * rs * lng_lds[col] + lnb_lds[col];
                scr[wv][r * NC + (col ^ ((r & 7) << 3))] = f2bf(xn);
            }
        }

        // w_proj GEMM + store
        Frag A3[4];
#pragma unroll
        for (int ks = 0; ks < 4; ks++) {
            int rowt = lane & 15;
            int c0 = ks * 32 + ((lane >> 4) << 3);
            A3[ks].u = *(const u16x8*)&scr[wv][rowt * NC + (c0 ^ ((rowt & 7) << 3))];
        }
        f32x4 C3[8];
        gemm8(A3, wfrag, 3, lane, C3);
#pragma unroll
        for (int nt = 0; nt < 8; nt++) {
            int col = nt * 16 + (lane & 15);
            float bp = bproj_lds[col];
#pragma unroll
            for (int reg = 0; reg < 4; reg++) {
                int gt = t0 + ((lane >> 4) << 2) + reg;
                if (gt < NTOK) outb[(size_t)gt * NC + col] = C3[nt][reg] + bp;
            }
        }
    }
}

extern "C" void kernel_launch(void* const* d_in, const int* in_sizes, int n_in,
                              void* d_out, int out_size, void* d_ws, size_t ws_size,
                              hipStream_t stream) {
    const float* x       = (const float*)d_in[0];
    const float* mask    = (const float*)d_in[1];
    const float* w_value = (const float*)d_in[2];
    const float* b_value = (const float*)d_in[3];
    const float* w_off   = (const float*)d_in[4];
    const float* b_off   = (const float*)d_in[5];
    const float* w_attn  = (const float*)d_in[6];
    const float* b_attn  = (const float*)d_in[7];
    const float* w_out   = (const float*)d_in[8];
    const float* b_out   = (const float*)d_in[9];
    const float* w_proj  = (const float*)d_in[10];
    const float* b_proj  = (const float*)d_in[11];
    const float* ln_g    = (const float*)d_in[12];
    const float* ln_b    = (const float*)d_in[13];
    float* out = (float*)d_out;

    u16* wfrag = (u16*)d_ws;
    float* colsum = (float*)((char*)d_ws + 131072);

    prep_kernel<<<33, 256, 0, stream>>>(w_value, w_off, w_attn, w_out, w_proj,
                                        wfrag, colsum);

    int Bt = in_sizes[0] / (NTOK * NC);
    fused_kernel<<<Bt, 512, 0, stream>>>(x, mask, wfrag, colsum,
                                         b_value, b_off, b_attn, b_out, b_proj,
                                         ln_g, ln_b, out);
}

// Round 2
// 152.395 us; speedup vs baseline: 1.5709x; 1.5709x over previous
//
#include <hip/hip_runtime.h>
#include <hip/hip_fp16.h>

#define NTOK 392
#define NC 128
#define VNC (NTOK * NC)
#define STRIPS 25
#define PI_F 3.14159265358979323846f

typedef __bf16 bf16_t;
typedef bf16_t bf16x8 __attribute__((ext_vector_type(8)));
typedef unsigned short u16;
typedef u16 u16x8 __attribute__((ext_vector_type(8)));
typedef float f32x4 __attribute__((ext_vector_type(4)));

union Frag { u16x8 u; bf16x8 b; };

__device__ __forceinline__ u16 f2bf(float f) {
    unsigned u = __float_as_uint(f);
    unsigned r = (u + 0x7FFFu + ((u >> 16) & 1u)) >> 16;
    return (u16)r;
}
__device__ __forceinline__ float bf2f(u16 u) {
    return __uint_as_float(((unsigned)u) << 16);
}

// ---------------------------------------------------------------------------
// prep kernel: weights -> bf16 MFMA-B-fragment-linear layout + colsums
// wfrag[set][nt][ks][lane][8] : elem i = W_set[k=ks*32+(lane>>4)*8+i][col=nt*16+(lane&15)]
// ---------------------------------------------------------------------------
__global__ void prep_kernel(const float* __restrict__ w_value,
                            const float* __restrict__ w_off,
                            const float* __restrict__ w_attn,
                            const float* __restrict__ w_out,
                            const float* __restrict__ w_proj,
                            u16* __restrict__ wfrag,
                            float* __restrict__ colsum) {
    int g = blockIdx.x * 256 + threadIdx.x;
    if (g < 8192) {
        int lane = g & 63;
        int ks = (g >> 6) & 3;
        int nt = (g >> 8) & 7;
        int set = g >> 11;
        int col = nt * 16 + (lane & 15);
        int k0 = ks * 32 + ((lane >> 4) << 3);
#pragma unroll
        for (int i = 0; i < 8; i++) {
            int k = k0 + i;
            float v;
            if (set == 0)      v = w_value[k * 128 + col];
            else if (set == 1) v = (col < 96) ? w_off[k * 96 + col] : w_attn[k * 32 + col - 96];
            else if (set == 2) v = w_out[k * 128 + col];
            else               v = w_proj[k * 128 + col];
            wfrag[(size_t)g * 8 + i] = f2bf(v);
        }
    } else if (g < 8192 + 128) {
        int o = g - 8192;
        float s = 0.f;
        for (int c2 = 0; c2 < 128; c2++)
            s += (o < 96) ? w_off[c2 * 96 + o] : w_attn[c2 * 32 + o - 96];
        colsum[o] = s;
    }
}

// A-frags in regs, B-frags streamed from global fraglinear table (L2-hot).
__device__ __forceinline__ void gemm8(const Frag* A, const u16* __restrict__ wf,
                                      int set, int lane, f32x4* C) {
#pragma unroll
    for (int nt = 0; nt < 8; nt++) {
        f32x4 acc = {0.f, 0.f, 0.f, 0.f};
#pragma unroll
        for (int ks = 0; ks < 4; ks++) {
            Frag B;
            B.u = *(const u16x8*)(wf + ((size_t)(((set * 8 + nt) * 4 + ks) * 64 + lane)) * 8);
            acc = __builtin_amdgcn_mfma_f32_16x16x32_bf16(A[ks].b, B.b, acc, 0, 0, 0);
        }
        C[nt] = acc;
    }
}

__device__ __forceinline__ u16x8 pack8(float4 a, float4 b) {
    u16x8 r;
    r[0] = f2bf(a.x); r[1] = f2bf(a.y); r[2] = f2bf(a.z); r[3] = f2bf(a.w);
    r[4] = f2bf(b.x); r[5] = f2bf(b.y); r[6] = f2bf(b.z); r[7] = f2bf(b.w);
    return r;
}

// block swizzle: window w -> XCD w%8; 7 blocks per window stay on one XCD
__device__ __forceinline__ void decode_bid(int bid, int& w, int& g) {
    int xcd = bid & 7;
    int q = bid >> 3;
    g = q % 7;
    w = ((q / 7) << 3) | xcd;
}

// ---------------------------------------------------------------------------
// K1: value = x @ w_value + b_value -> bf16 grid in ws; diag from mask -> ws
// grid: Bt*7 blocks x 256 thr; each wave one 16-token strip
// ---------------------------------------------------------------------------
__global__ __launch_bounds__(256, 4) void value_kernel(
    const float* __restrict__ x, const float* __restrict__ mask,
    const u16* __restrict__ wfrag, const float* __restrict__ b_value,
    u16* __restrict__ value_ws, float* __restrict__ diag_ws) {
    int w, g;
    decode_bid(blockIdx.x, w, g);
    int lane = threadIdx.x & 63;
    int wv = threadIdx.x >> 6;
    int s = g * 4 + wv;
    if (s >= STRIPS) return;
    int t0 = s * 16;
    const float* xb = x + (size_t)w * VNC;

    // diag for this strip's 16 tokens (lanes 0..15)
    if (lane < 16) {
        int n = t0 + lane;
        if (n < NTOK) {
            int d = n / 49; int rr = n - d * 49; int h = rr / 7; int ww = rr - h * 7;
            const float* mb = mask + ((size_t)w * NTOK + n) * NTOK;
            float sz = 0.f, sy = 0.f, sx = 0.f;
            for (int k = 0; k <= d; k++) sz += mb[k * 49 + h * 7 + ww];
            for (int k = 0; k <= h; k++) sy += mb[d * 49 + k * 7 + ww];
            for (int k = 0; k <= ww; k++) sx += mb[d * 49 + h * 7 + k];
            float m = mb[d * 49 + h * 7 + ww];
            float xe = sx * m / PI_F, ye = sy * m / PI_F, ze = sz * m / PI_F;
            diag_ws[w * NTOK + n] = m * (sinf(xe) + sinf(PI_F * ye) + ze);
        }
    }

    int arow = t0 + (lane & 15); if (arow > NTOK - 1) arow = NTOK - 1;
    Frag A[4];
#pragma unroll
    for (int ks = 0; ks < 4; ks++) {
        const float4* p = (const float4*)(xb + (size_t)arow * NC + ks * 32 + ((lane >> 4) << 3));
        A[ks].u = pack8(p[0], p[1]);
    }
    f32x4 C[8];
    gemm8(A, wfrag, 0, lane, C);
    u16* vb = value_ws + (size_t)w * VNC;
#pragma unroll
    for (int nt = 0; nt < 8; nt++) {
        int col = nt * 16 + (lane & 15);
        float bv = b_value[col];
#pragma unroll
        for (int reg = 0; reg < 4; reg++) {
            int r = t0 + ((lane >> 4) << 2) + reg;
            if (r < NTOK) vb[r * NC + col] = f2bf(C[nt][reg] + bv);
        }
    }
}

// ---------------------------------------------------------------------------
// K2: off/attn GEMM -> softmax -> trilinear sample (value gathered from L2)
//     -> w_out GEMM -> residual+LN -> w_proj GEMM -> out
// grid: Bt*7 blocks x 256 thr; each wave one 16-token strip, wave-local scr
// ---------------------------------------------------------------------------
__global__ __launch_bounds__(256, 4) void attn_kernel(
    const float* __restrict__ x, const u16* __restrict__ wfrag,
    const float* __restrict__ colsum_ws, const u16* __restrict__ value_ws,
    const float* __restrict__ diag_ws,
    const float* __restrict__ b_off, const float* __restrict__ b_attn,
    const float* __restrict__ b_out, const float* __restrict__ b_proj,
    const float* __restrict__ ln_g, const float* __restrict__ ln_b,
    float* __restrict__ out) {
    __shared__ u16 scr[4][2048];
    __shared__ float colsum_lds[128], bias2_lds[128], bout_lds[128];
    __shared__ float lng_lds[128], lnb_lds[128], bproj_lds[128];

    int w, g;
    decode_bid(blockIdx.x, w, g);
    int tid = threadIdx.x;
    int lane = tid & 63;
    int wv = tid >> 6;

    if (tid < 128) {
        colsum_lds[tid] = colsum_ws[tid];
        bias2_lds[tid] = (tid < 96) ? b_off[tid] : b_attn[tid - 96];
        bout_lds[tid] = b_out[tid];
        lng_lds[tid] = ln_g[tid];
        lnb_lds[tid] = ln_b[tid];
        bproj_lds[tid] = b_proj[tid];
    }
    __syncthreads();

    int s = g * 4 + wv;
    if (s >= STRIPS) return;
    int t0 = s * 16;
    const float* xb = x + (size_t)w * VNC;
    const u16* vb = value_ws + (size_t)w * VNC;
    float* outb = out + (size_t)w * VNC;

    // ---- off/attn GEMM ----
    int arow = t0 + (lane & 15); if (arow > NTOK - 1) arow = NTOK - 1;
    Frag A1[4];
#pragma unroll
    for (int ks = 0; ks < 4; ks++) {
        const float4* p = (const float4*)(xb + (size_t)arow * NC + ks * 32 + ((lane >> 4) << 3));
        A1[ks].u = pack8(p[0], p[1]);
    }
    f32x4 C1[8];
    gemm8(A1, wfrag, 1, lane, C1);

    // diag*colsum + bias; softmax over 4 attn logits (4 adjacent lanes)
#pragma unroll
    for (int nt = 0; nt < 8; nt++) {
        int col = nt * 16 + (lane & 15);
        float cs = colsum_lds[col];
        float b2 = bias2_lds[col];
#pragma unroll
        for (int reg = 0; reg < 4; reg++) {
            int r = ((lane >> 4) << 2) + reg;
            int gt = t0 + r;
            float dg = diag_ws[w * NTOK + (gt < NTOK ? gt : NTOK - 1)];
            float v = C1[nt][reg] + dg * cs + b2;
            if (nt < 6) {
                scr[wv][r * 96 + col] = __half_as_ushort(__float2half(v));
            } else {
                float m = fmaxf(v, __shfl_xor(v, 1));
                m = fmaxf(m, __shfl_xor(m, 2));
                float e = expf(v - m);
                float s2 = e + __shfl_xor(e, 1);
                s2 += __shfl_xor(s2, 2);
                scr[wv][1536 + r * 32 + (col - 96)] =
                    __half_as_ushort(__float2half(e / s2));
            }
        }
    }

    // ---- trilinear sampling: lane -> (token = j*8 + lane>>3, head = lane&7) ----
    float acc[2][16];
#pragma unroll
    for (int j = 0; j < 2; j++)
#pragma unroll
        for (int e = 0; e < 16; e++) acc[j][e] = 0.f;

#pragma unroll
    for (int j = 0; j < 2; j++) {
        int t = j * 8 + (lane >> 3);
        int hh = lane & 7;
        int gt = t0 + t;
        int gtc = gt < NTOK ? gt : NTOK - 1;
        int dd = gtc / 49; int rr = gtc - dd * 49;
        int hy = rr / 7;   int wq = rr - hy * 7;
#pragma unroll
        for (int p = 0; p < 4; p++) {
            int ob = t * 96 + (hh * 4 + p) * 3;
            float ox = __half2float(__ushort_as_half(scr[wv][ob + 0]));
            float oy = __half2float(__ushort_as_half(scr[wv][ob + 1]));
            float oz = __half2float(__ushort_as_half(scr[wv][ob + 2]));
            float aw = __half2float(__ushort_as_half(scr[wv][1536 + t * 32 + hh * 4 + p]));
            float px = (float)wq + ox;
            float py = (float)hy + oy;
            float pz = (float)dd + oz;
            float fx = floorf(px), fy = floorf(py), fz = floorf(pz);
            float wxf = px - fx, wyf = py - fy, wzf = pz - fz;
            int ix = (int)fx, iy = (int)fy, iz = (int)fz;
#pragma unroll
            for (int c = 0; c < 8; c++) {
                int dx = c & 1, dy = (c >> 1) & 1, dz = c >> 2;
                int xi = ix + dx, yi = iy + dy, zi = iz + dz;
                if (xi < 0 || xi >= 7 || yi < 0 || yi >= 7 || zi < 0 || zi >= 8) continue;
                float wgt = (dx ? wxf : 1.f - wxf) * (dy ? wyf : 1.f - wyf)
                          * (dz ? wzf : 1.f - wzf) * aw;
                const u16x8* vp = (const u16x8*)(vb + (zi * 49 + yi * 7 + xi) * NC + hh * 16);
                u16x8 v0 = vp[0], v1 = vp[1];
#pragma unroll
                for (int e = 0; e < 8; e++) {
                    acc[j][e]     += wgt * bf2f(v0[e]);
                    acc[j][8 + e] += wgt * bf2f(v1[e]);
                }
            }
        }
    }

    // attnout strip -> scratch (bf16, XOR-swizzled for conflict-free A-frag reads)
#pragma unroll
    for (int j = 0; j < 2; j++) {
        int t = j * 8 + (lane >> 3);
        int hh = lane & 7;
        int sw = (t & 7) << 3;
        u16x8 o0, o1;
#pragma unroll
        for (int e = 0; e < 8; e++) { o0[e] = f2bf(acc[j][e]); o1[e] = f2bf(acc[j][8 + e]); }
        *(u16x8*)&scr[wv][t * NC + ((hh * 16) ^ sw)] = o0;
        *(u16x8*)&scr[wv][t * NC + ((hh * 16 + 8) ^ sw)] = o1;
    }

    // ---- w_out GEMM ----
    Frag A2[4];
#pragma unroll
    for (int ks = 0; ks < 4; ks++) {
        int rowt = lane & 15;
        int c0 = ks * 32 + ((lane >> 4) << 3);
        A2[ks].u = *(const u16x8*)&scr[wv][rowt * NC + (c0 ^ ((rowt & 7) << 3))];
    }
    f32x4 C2[8];
    gemm8(A2, wfrag, 2, lane, C2);

    // ---- residual + LayerNorm (fp32), staged bf16 back to scratch ----
#pragma unroll
    for (int reg = 0; reg < 4; reg++) {
        int r = ((lane >> 4) << 2) + reg;
        int gt = t0 + r;
        int gtc = gt < NTOK ? gt : NTOK - 1;
        float vrow[8];
        float sm = 0.f, sq = 0.f;
#pragma unroll
        for (int nt = 0; nt < 8; nt++) {
            int col = nt * 16 + (lane & 15);
            float v = C2[nt][reg] + bout_lds[col] + xb[(size_t)gtc * NC + col];
            vrow[nt] = v; sm += v; sq += v * v;
        }
        sm += __shfl_xor(sm, 1); sm += __shfl_xor(sm, 2);
        sm += __shfl_xor(sm, 4); sm += __shfl_xor(sm, 8);
        sq += __shfl_xor(sq, 1); sq += __shfl_xor(sq, 2);
        sq += __shfl_xor(sq, 4); sq += __shfl_xor(sq, 8);
        float mu = sm * (1.f / 128.f);
        float var = sq * (1.f / 128.f) - mu * mu;
        float rs = rsqrtf(var + 1e-5f);
#pragma unroll
        for (int nt = 0; nt < 8; nt++) {
            int col = nt * 16 + (lane & 15);
            float xn = (vrow[nt] - mu) * rs * lng_lds[col] + lnb_lds[col];
            scr[wv][r * NC + (col ^ ((r & 7) << 3))] = f2bf(xn);
        }
    }

    // ---- w_proj GEMM + store ----
    Frag A3[4];
#pragma unroll
    for (int ks = 0; ks < 4; ks++) {
        int rowt = lane & 15;
        int c0 = ks * 32 + ((lane >> 4) << 3);
        A3[ks].u = *(const u16x8*)&scr[wv][rowt * NC + (c0 ^ ((rowt & 7) << 3))];
    }
    f32x4 C3[8];
    gemm8(A3, wfrag, 3, lane, C3);
#pragma unroll
    for (int nt = 0; nt < 8; nt++) {
        int col = nt * 16 + (lane & 15);
        float bp = bproj_lds[col];
#pragma unroll
        for (int reg = 0; reg < 4; reg++) {
            int gt = t0 + ((lane >> 4) << 2) + reg;
            if (gt < NTOK) outb[(size_t)gt * NC + col] = C3[nt][reg] + bp;
        }
    }
}

extern "C" void kernel_launch(void* const* d_in, const int* in_sizes, int n_in,
                              void* d_out, int out_size, void* d_ws, size_t ws_size,
                              hipStream_t stream) {
    const float* x       = (const float*)d_in[0];
    const float* mask    = (const float*)d_in[1];
    const float* w_value = (const float*)d_in[2];
    const float* b_value = (const float*)d_in[3];
    const float* w_off   = (const float*)d_in[4];
    const float* b_off   = (const float*)d_in[5];
    const float* w_attn  = (const float*)d_in[6];
    const float* b_attn  = (const float*)d_in[7];
    const float* w_out   = (const float*)d_in[8];
    const float* b_out   = (const float*)d_in[9];
    const float* w_proj  = (const float*)d_in[10];
    const float* b_proj  = (const float*)d_in[11];
    const float* ln_g    = (const float*)d_in[12];
    const float* ln_b    = (const float*)d_in[13];
    float* out = (float*)d_out;

    u16* wfrag    = (u16*)d_ws;                              // 131072 B
    float* colsum = (float*)((char*)d_ws + 131072);          // 512 B
    float* diag_ws = (float*)((char*)d_ws + 131584);         // Bt*392*4 = 401408 B
    u16* value_ws = (u16*)((char*)d_ws + 532992);            // Bt*392*128*2 = 25.7 MB

    prep_kernel<<<33, 256, 0, stream>>>(w_value, w_off, w_attn, w_out, w_proj,
                                        wfrag, colsum);

    int Bt = in_sizes[0] / VNC;
    int nblk = Bt * 7;
    value_kernel<<<nblk, 256, 0, stream>>>(x, mask, wfrag, b_value,
                                           value_ws, diag_ws);
    attn_kernel<<<nblk, 256, 0, stream>>>(x, wfrag, colsum, value_ws, diag_ws,
                                          b_off, b_attn, b_out, b_proj,
                                          ln_g, ln_b, out);
}